// Round 9
// baseline (202.906 us; speedup 1.0000x reference)
//
#include <hip/hip_runtime.h>
#include <math.h>

#define BB   4
#define HH   96
#define WW   96
#define HW   (HH * WW)          // 9216
#define CIN  64
#define COUT 64
#define C2B  192                // bf16 row: fi[64] fj[64](permuted) flow[2] pad
#define NROW (BB * HW)          // 36864
#define ZROW NROW               // all-zero row
#define NSTRIP (NROW / 16)      // 2304 strips of 16 positions
#define BPX3 (NSTRIP / 8)       // 288 strips per XCD slice
#define GRID 768                // fused blocks; 3 strips each (2304 = 768*3)
#define NA   (9 * 5 * 2 * 512)  // wa2f elements (46080), fragment-dense
#define NW   (9 * 2 * 4 * 512)  // wb2f elements (36864), fragment-dense
#define PXB2 (NROW / 32)        // 1152 prep X-blocks (64 rows, half channels)
#define PWBLK 324               // weight blocks covering NA+NW elements
#define TSX  35                 // prep LDS tile stride (dwords), conflict-free
#define PR   55                 // patch row-dim (54 rows + 1 pad)

typedef short v8s __attribute__((ext_vector_type(8)));   // 8 bf16 = 4 VGPRs
typedef float v4f __attribute__((ext_vector_type(4)));

__device__ __forceinline__ unsigned short f2bf(float f) {
    unsigned u = __float_as_uint(f);
    return (unsigned short)((u + 0x7FFFu + ((u >> 16) & 1u)) >> 16);  // RTN-even
}
__device__ __forceinline__ unsigned pack2(float a, float b) {
    return (unsigned)f2bf(a) | ((unsigned)f2bf(b) << 16);
}
__device__ __forceinline__ unsigned bil2(unsigned a, unsigned b, unsigned c,
                                         unsigned d, float w00, float w01,
                                         float w10, float w11) {
    float lo = w00 * __uint_as_float(a << 16) + w01 * __uint_as_float(b << 16)
             + w10 * __uint_as_float(c << 16) + w11 * __uint_as_float(d << 16);
    float hi = w00 * __uint_as_float(a & 0xffff0000u)
             + w01 * __uint_as_float(b & 0xffff0000u)
             + w10 * __uint_as_float(c & 0xffff0000u)
             + w11 * __uint_as_float(d & 0xffff0000u);
    return pack2(lo, hi);
}

// ---------------------------------------------------------------------------
// Prep (unchanged, known-good R7). Emits xt (conv layout), weight fragments,
// and vt[b][plane][pos] (plane-major gather mirror, 16 B per position).
// ---------------------------------------------------------------------------
__global__ __launch_bounds__(256) void prep_kernel(
    const float* __restrict__ fi, const float* __restrict__ fj,
    const float* __restrict__ fl, const float* __restrict__ w_off,
    const float* __restrict__ w_mod, const float* __restrict__ w_reg,
    unsigned short* __restrict__ xt, unsigned short* __restrict__ wa2f,
    unsigned short* __restrict__ wb2f, uint4* __restrict__ vt)
{
    int blk = blockIdx.x;
    if (blk < PXB2) {
        __shared__ __align__(16) unsigned tile[64 * TSX];  // 9 KB
        int tid = threadIdx.x;
        int p = tid & 63, cg = tid >> 6;    // position, channel-group 0..3
        int u = blk >> 1, half = blk & 1;
        int r0 = u * 64;
        int b = r0 / HW;                    // 64-row strip never straddles b
        int hwb = r0 - b * HW;              // strip base within image
        int hw = hwb + p;
        uint4* dst = (uint4*)(xt + (size_t)r0 * C2B);      // 24 quads per row
        if (half == 0) {                    // fi -> chunks 0..7
            const float* pi = fi + (size_t)b * CIN * HW + hw;
#pragma unroll
            for (int d = 0; d < 8; ++d) {
                int c = cg * 16 + 2 * d;
                tile[p * TSX + cg * 8 + d] =
                    pack2(pi[(size_t)c * HW], pi[(size_t)(c + 1) * HW]);
            }
            __syncthreads();
#pragma unroll
            for (int i = 0; i < 2; ++i) {   // 512 quads: 8 per row
                int gq = i * 256 + tid;
                int rl = gq >> 3, c4 = gq & 7;
                const unsigned* s = &tile[rl * TSX + c4 * 4];
                uint4 v = {s[0], s[1], s[2], s[3]};
                dst[rl * 24 + c4] = v;
            }
        } else {                            // fj(permuted)+flow+pad -> 8..23
            const float* pj = fj + (size_t)b * CIN * HW + hw;
#pragma unroll
            for (int d = 0; d < 8; ++d) {
                int c = cg * 16 + 2 * d;
                tile[p * TSX + cg * 8 + d] =
                    pack2(pj[(size_t)c * HW], pj[(size_t)(c + 1) * HW]);
            }
            if (cg == 0) {
                const float* pf = fl + (size_t)b * 2 * HW + hw;
                tile[p * TSX + 32] = pack2(pf[0], pf[HW]);
            }
            __syncthreads();
#pragma unroll
            for (int i = 0; i < 4; ++i) {   // 1024 quads: 16 per row (8..23)
                int gq = i * 256 + tid;
                int rl = gq >> 4, c4 = gq & 15;
                uint4 v = {0u, 0u, 0u, 0u};
                if (c4 < 8) {
                    const unsigned* s = &tile[rl * TSX + c4 * 4];
                    v.x = s[0]; v.y = s[1]; v.z = s[2]; v.w = s[3];
                } else if (c4 == 8) {
                    v.x = tile[rl * TSX + 32];
                }
                int pc4 = (c4 < 8) ? ((c4 & 3) * 2 + (c4 >> 2)) : c4;  // permute
                dst[rl * 24 + 8 + pc4] = v;
            }
            // vt mirror: plane pl (phys chunk), 64 consecutive positions.
#pragma unroll
            for (int i = 0; i < 2; ++i) {
                int it = i * 256 + tid;
                int pl = it >> 6, rl = it & 63;
                int o  = (pl >> 1) + (pl & 1) * 4;
                const unsigned* s = &tile[rl * TSX + o * 4];
                uint4 v = {s[0], s[1], s[2], s[3]};
                vt[((size_t)(b * 8 + pl)) * HW + hwb + rl] = v;
            }
        }
    } else if (blk < PXB2 + PWBLK) {
        int e = (blk - PXB2) * 256 + threadIdx.x;
        if (e < NA) {                       // wa2f, fragment-dense
            int t  = e / 5120;
            int r1 = e - t * 5120;
            int ks = r1 >> 10;
            int r2 = r1 & 1023;
            int nt = r2 >> 9;
            int l9 = r2 & 511;
            int l  = l9 >> 3, ee = l9 & 7;
            int m  = l & 15, g = l >> 4;
            int oc = nt * 16 + m;
            int ch = ks * 32 + g * 8 + ee;
            float v = 0.0f;
            if (oc < 27 && ch < 130) {
                if (oc < 18) v = w_off[((size_t)oc * 130 + ch) * 9 + t];
                else         v = w_mod[((size_t)(oc - 18) * 130 + ch) * 9 + t];
            }
            wa2f[e] = f2bf(v);
        } else {
            int e2 = e - NA;
            if (e2 < NW) {                  // wb2f, fragment-dense
                int k  = e2 >> 12;
                int r1 = e2 & 4095;
                int ks = r1 >> 11;
                int r2 = r1 & 2047;
                int nt = r2 >> 9;
                int l9 = r2 & 511;
                int l  = l9 >> 3, ee = l9 & 7;
                int m  = l & 15, g = l >> 4;
                int o  = nt * 16 + m;
                int c  = ks * 32 + g * 8 + ee;
                wb2f[e2] = f2bf(w_reg[((size_t)o * 64 + c) * 9 + k]);
            }
        }
    } else {
        if (threadIdx.x < 24) {             // zero row, 24 dwordx4
            uint4 z = {0u, 0u, 0u, 0u};
            ((uint4*)(xt + (size_t)ZROW * C2B))[threadIdx.x] = z;
        }
    }
}

// ---------------------------------------------------------------------------
// Fused conv + deform. R23 = R21 body, 3 strips per block (GRID=768) with a
// register prefetch pipeline: strip i+1's 1080 staging quads are loaded into
// registers right after barrier S of strip i and written to LDS at the top of
// iteration i+1. LDS destinations are strip-invariant (function of tid only).
// Load drain happens at the next barrier (compiler vmcnt(0)), which is a full
// phase-1 MFMA chain away -> staging latency hidden for strips 1,2.
// __launch_bounds__(512,6): <=84 VGPR for the ~12-reg prefetch; 3 blocks/CU.
// ---------------------------------------------------------------------------
__global__ __launch_bounds__(512, 6) void fused_kernel(
    const unsigned short* __restrict__ xt,
    const unsigned short* __restrict__ wa2f,
    const unsigned short* __restrict__ wb2f,
    const uint4* __restrict__ vt,
    const float* __restrict__ b_off, const float* __restrict__ b_mod,
    float* __restrict__ out)
{
    // pool: [0,17600) patch4 (stage..barrier A) | [0,16384) red2 (after B)
    __shared__ __align__(16) unsigned char pool[17600];
    __shared__ __align__(16) float red1[8][8][64];    // 16 KB ph1 partials
    __shared__ float lraw[16 * 28];                   // 1.8 KB offsets/mods

    uint4* patch4 = (uint4*)pool;
    float* red2   = (float*)pool;                     // [4][16][64]

    int tid = threadIdx.x;
    int l = tid & 63;
    int wid = __builtin_amdgcn_readfirstlane(tid >> 6);  // 0..7
    int m = l & 15, g = l >> 4;
    int bx = blockIdx.x;

    // strip-invariant LDS offsets for this thread's 3 staging items
    int it0 = tid, it1 = tid + 512, it2 = tid + 1024;   // it2 valid if tid<56
    int run0 = it0 / 360, rm0 = it0 - run0 * 360;
    int r180 = rm0 / 20,  c80 = rm0 - r180 * 20;
    int run1 = it1 / 360, rm1 = it1 - run1 * 360;
    int r181 = rm1 / 20,  c81 = rm1 - r181 * 20;
    int run2 = it2 / 360, rm2 = it2 - run2 * 360;
    int r182 = rm2 / 20,  c82 = rm2 - r182 * 20;
    int lo0 = c80 * PR + run0 * 18 + r180;
    int lo1 = c81 * PR + run1 * 18 + r181;
    int lo2 = c82 * PR + run2 * 18 + r182;

    // load one staging item for strip geometry (b, y0b, x0b)
    auto ld_item = [&](int b, int y0b, int x0b, int run, int r18, int c8) {
        int yy = y0b + run - 1;
        int xx = x0b - 1 + r18;
        bool ok = ((unsigned)yy < HH) && ((unsigned)xx < WW);
        uint4 v = {0u, 0u, 0u, 0u};
        if (ok)
            v = ((const uint4*)(xt + (size_t)(b * HW + yy * WW + xx) * C2B))[c8];
        return v;
    };

    auto geom = [&](int sj, int& b, int& hw0) {
        int strip = (sj & 7) * BPX3 + (sj >> 3);    // XCD-contiguous
        b = strip / (HW / 16);
        hw0 = (strip - b * (HW / 16)) * 16;
    };

    // ---- prologue: prefetch strip 0 ----
    uint4 pf0, pf1, pf2;
    {
        int b, hw0; geom(bx, b, hw0);
        int y0b = hw0 / WW, x0b = hw0 - y0b * WW;
        pf0 = ld_item(b, y0b, x0b, run0, r180, c80);
        pf1 = ld_item(b, y0b, x0b, run1, r181, c81);
        pf2 = (tid < 56) ? ld_item(b, y0b, x0b, run2, r182, c82)
                         : (uint4){0u, 0u, 0u, 0u};
    }

#pragma unroll 1
    for (int i = 0; i < 3; ++i) {
        int sj = bx + i * GRID;
        int b, hw0; geom(sj, b, hw0);
        int hw = hw0 + m;
        int x = hw % WW, y = hw / WW;

        // ---- write prefetched patch to LDS ----
        patch4[lo0] = pf0;
        patch4[lo1] = pf1;
        if (tid < 56) patch4[lo2] = pf2;
        __syncthreads();                    // barrier S

        // ---- issue prefetch for strip i+1 (overlaps phase 1+2) ----
        if (i < 2) {
            int bn, hn; geom(sj + GRID, bn, hn);
            int y0n = hn / WW, x0n = hn - y0n * WW;
            pf0 = ld_item(bn, y0n, x0n, run0, r180, c80);
            pf1 = ld_item(bn, y0n, x0n, run1, r181, c81);
            if (tid < 56) pf2 = ld_item(bn, y0n, x0n, run2, r182, c82);
        }

        // ---- Phase 1: conv partials, 45 units over 8 waves ----
        v4f acc0 = {0.f, 0.f, 0.f, 0.f};
        v4f acc1 = {0.f, 0.f, 0.f, 0.f};
        {
            int nu = (wid < 5) ? 6 : 5;     // wave-uniform unit count
#pragma unroll
            for (int ii = 0; ii < 6; ++ii) {
                if (ii < nu) {
                    int u = wid + 8 * ii;   // unit = t*5+ks, uniform
                    int t = u / 5, ks = u - 5 * t;
                    int r = (t / 3) * 18 + (t % 3) + m;
                    int c8 = (ks == 0) ? g : (ks == 1) ? 4 + g
                           : (ks == 2) ? 8 + 2 * g : (ks == 3) ? 9 + 2 * g
                           : 16 + g;
                    v8s a = *(const v8s*)&patch4[c8 * PR + r];
                    const unsigned short* wp =
                        wa2f + ((size_t)(u * 2)) * 512 + l * 8;
                    v8s b0 = *(const v8s*)(wp);
                    v8s b1 = *(const v8s*)(wp + 512);
                    acc0 = __builtin_amdgcn_mfma_f32_16x16x32_bf16(a, b0, acc0, 0, 0, 0);
                    acc1 = __builtin_amdgcn_mfma_f32_16x16x32_bf16(a, b1, acc1, 0, 0, 0);
                }
            }
        }

        {                                   // publish 8 dwords/lane (scalar)
#pragma unroll
            for (int j = 0; j < 4; ++j) red1[wid][j][l] = acc0[j];
#pragma unroll
            for (int j = 0; j < 4; ++j) red1[wid][4 + j][l] = acc1[j];
        }
        __syncthreads();                    // barrier A (patch4 dead)

        {   // reduce + epilogue: wave w owns output-dword slot j = w
            int j = wid;
            float v = 0.f;
#pragma unroll
            for (int sw = 0; sw < 8; ++sw) v += red1[sw][j][l];
            int r = j & 3;
            int oc = (j < 4) ? m : 16 + m;
            int pos = g * 4 + r;
            if (oc < 18) {
                lraw[pos * 28 + oc] = v + b_off[oc];
            } else if (oc < 27) {
                lraw[pos * 28 + oc] =
                    2.0f / (1.0f + __expf(-(v + b_mod[oc - 18])));
            }
        }
        __syncthreads();                    // barrier B (red1 dead, red2 born)

        // ---- Phase 2: wave w owns tap w; tap 8 split by ks to waves 6/7 ----
        v4f acc[4];
#pragma unroll
        for (int nt = 0; nt < 4; ++nt) acc[nt] = (v4f){0.f, 0.f, 0.f, 0.f};

        auto do_tap = [&](int k) {
            int ky = k / 3, kx = k - 3 * ky;
            float dy = lraw[m * 28 + 2 * k];
            float dx = lraw[m * 28 + 2 * k + 1];
            float mm = lraw[m * 28 + 18 + k];

            float py = (float)(y - 1 + ky) + dy;
            float px = (float)(x - 1 + kx) + dx;
            float fy = floorf(py), fx = floorf(px);
            int   y0 = (int)fy,    x0 = (int)fx;
            float wy = py - fy,    wx = px - fx;
            int   y1 = y0 + 1,     x1 = x0 + 1;

            bool y0v = (y0 >= 0) && (y0 < HH);
            bool y1v = (y1 >= 0) && (y1 < HH);
            bool x0v = (x0 >= 0) && (x0 < WW);
            bool x1v = (x1 >= 0) && (x1 < WW);

            float w00 = (1.f - wy) * (1.f - wx) * ((y0v && x0v) ? mm : 0.f);
            float w01 = (1.f - wy) * wx         * ((y0v && x1v) ? mm : 0.f);
            float w10 = wy * (1.f - wx)         * ((y1v && x0v) ? mm : 0.f);
            float w11 = wy * wx                 * ((y1v && x1v) ? mm : 0.f);

            int y0c = min(max(y0, 0), HH - 1), y1c = min(max(y1, 0), HH - 1);
            int x0c = min(max(x0, 0), WW - 1), x1c = min(max(x1, 0), WW - 1);
            int i00 = y0c * WW + x0c, i01 = y0c * WW + x1c;
            int i10 = y1c * WW + x0c, i11 = y1c * WW + x1c;

            const uint4* p0 = vt + ((size_t)(b * 8 + 2 * g + 0)) * HW;
            const uint4* p1 = vt + ((size_t)(b * 8 + 2 * g + 1)) * HW;

            uint4 a00 = p0[i00];
            uint4 a01 = p0[i01];
            uint4 a10 = p0[i10];
            uint4 a11 = p0[i11];
            uint4 c00 = p1[i00];
            uint4 c01 = p1[i01];
            uint4 c10 = p1[i10];
            uint4 c11 = p1[i11];

            uint4 ov0, ov1;
            ov0.x = bil2(a00.x, a01.x, a10.x, a11.x, w00, w01, w10, w11);
            ov0.y = bil2(a00.y, a01.y, a10.y, a11.y, w00, w01, w10, w11);
            ov0.z = bil2(a00.z, a01.z, a10.z, a11.z, w00, w01, w10, w11);
            ov0.w = bil2(a00.w, a01.w, a10.w, a11.w, w00, w01, w10, w11);
            ov1.x = bil2(c00.x, c01.x, c10.x, c11.x, w00, w01, w10, w11);
            ov1.y = bil2(c00.y, c01.y, c10.y, c11.y, w00, w01, w10, w11);
            ov1.z = bil2(c00.z, c01.z, c10.z, c11.z, w00, w01, w10, w11);
            ov1.w = bil2(c00.w, c01.w, c10.w, c11.w, w00, w01, w10, w11);
            v8s af0 = __builtin_bit_cast(v8s, ov0);
            v8s af1 = __builtin_bit_cast(v8s, ov1);

#pragma unroll
            for (int nt = 0; nt < 4; ++nt) {
                const unsigned short* wp0 =
                    wb2f + ((size_t)((k * 2 + 0) * 4 + nt)) * 512 + l * 8;
                const unsigned short* wp1 =
                    wb2f + ((size_t)((k * 2 + 1) * 4 + nt)) * 512 + l * 8;
                v8s bb0 = *(const v8s*)wp0;
                v8s bb1 = *(const v8s*)wp1;
                acc[nt] = __builtin_amdgcn_mfma_f32_16x16x32_bf16(af0, bb0, acc[nt], 0, 0, 0);
                acc[nt] = __builtin_amdgcn_mfma_f32_16x16x32_bf16(af1, bb1, acc[nt], 0, 0, 0);
            }
        };

        auto do_half = [&](int k, int ks) {
            int ky = k / 3, kx = k - 3 * ky;
            float dy = lraw[m * 28 + 2 * k];
            float dx = lraw[m * 28 + 2 * k + 1];
            float mm = lraw[m * 28 + 18 + k];

            float py = (float)(y - 1 + ky) + dy;
            float px = (float)(x - 1 + kx) + dx;
            float fy = floorf(py), fx = floorf(px);
            int   y0 = (int)fy,    x0 = (int)fx;
            float wy = py - fy,    wx = px - fx;
            int   y1 = y0 + 1,     x1 = x0 + 1;

            bool y0v = (y0 >= 0) && (y0 < HH);
            bool y1v = (y1 >= 0) && (y1 < HH);
            bool x0v = (x0 >= 0) && (x0 < WW);
            bool x1v = (x1 >= 0) && (x1 < WW);

            float w00 = (1.f - wy) * (1.f - wx) * ((y0v && x0v) ? mm : 0.f);
            float w01 = (1.f - wy) * wx         * ((y0v && x1v) ? mm : 0.f);
            float w10 = wy * (1.f - wx)         * ((y1v && x0v) ? mm : 0.f);
            float w11 = wy * wx                 * ((y1v && x1v) ? mm : 0.f);

            int y0c = min(max(y0, 0), HH - 1), y1c = min(max(y1, 0), HH - 1);
            int x0c = min(max(x0, 0), WW - 1), x1c = min(max(x1, 0), WW - 1);
            int i00 = y0c * WW + x0c, i01 = y0c * WW + x1c;
            int i10 = y1c * WW + x0c, i11 = y1c * WW + x1c;

            const uint4* pk = vt + ((size_t)(b * 8 + 2 * g + ks)) * HW;
            uint4 a00 = pk[i00];
            uint4 a01 = pk[i01];
            uint4 a10 = pk[i10];
            uint4 a11 = pk[i11];

            uint4 ov;
            ov.x = bil2(a00.x, a01.x, a10.x, a11.x, w00, w01, w10, w11);
            ov.y = bil2(a00.y, a01.y, a10.y, a11.y, w00, w01, w10, w11);
            ov.z = bil2(a00.z, a01.z, a10.z, a11.z, w00, w01, w10, w11);
            ov.w = bil2(a00.w, a01.w, a10.w, a11.w, w00, w01, w10, w11);
            v8s af = __builtin_bit_cast(v8s, ov);

#pragma unroll
            for (int nt = 0; nt < 4; ++nt) {
                const unsigned short* wp =
                    wb2f + ((size_t)((k * 2 + ks) * 4 + nt)) * 512 + l * 8;
                v8s bb = *(const v8s*)wp;
                acc[nt] = __builtin_amdgcn_mfma_f32_16x16x32_bf16(af, bb, acc[nt], 0, 0, 0);
            }
        };

        do_tap(wid);
        if (wid == 6) do_half(8, 0);
        if (wid == 7) do_half(8, 1);

        // ---- Two-stage cross-wave reduction (red2 = 4 buffers, 16 KB) ----
        if (wid >= 4) {                     // stage A: waves 4-7 publish
            float* rb = red2 + ((size_t)(wid - 4) * 16) * 64;
#pragma unroll
            for (int nt = 0; nt < 4; ++nt)
#pragma unroll
                for (int r = 0; r < 4; ++r)
                    rb[(nt * 4 + r) * 64 + l] = acc[nt][r];
        }
        __syncthreads();                    // barrier C1
        if (wid < 4) {                      // stage B: waves 0-3 add in place
            float* rb = red2 + ((size_t)wid * 16) * 64;
#pragma unroll
            for (int nt = 0; nt < 4; ++nt)
#pragma unroll
                for (int r = 0; r < 4; ++r) {
                    float t = rb[(nt * 4 + r) * 64 + l] + acc[nt][r];
                    rb[(nt * 4 + r) * 64 + l] = t;
                }
        }
        __syncthreads();                    // barrier C2
        {   // stage C: wave w reduces slots {nt*4+r0, +1} over 4 buffers
            int nt = wid >> 1, r0 = (wid & 1) * 2;
            float v0 = 0.f, v1 = 0.f;
#pragma unroll
            for (int bu = 0; bu < 4; ++bu) {
                v0 += red2[((size_t)bu * 16 + nt * 4 + r0) * 64 + l];
                v1 += red2[((size_t)bu * 16 + nt * 4 + r0 + 1) * 64 + l];
            }
            float* op = out + ((size_t)(b * COUT + nt * 16 + m)) * HW
                      + hw0 + g * 4 + r0;
            float2 s2 = {v0, v1};
            *(float2*)op = s2;
        }
        __syncthreads();                    // barrier E: protect pool reuse
    }
}

extern "C" void kernel_launch(void* const* d_in, const int* in_sizes, int n_in,
                              void* d_out, int out_size, void* d_ws, size_t ws_size,
                              hipStream_t stream)
{
    const float* frame_i = (const float*)d_in[0];
    const float* frame_j = (const float*)d_in[1];
    const float* flow_ij = (const float*)d_in[2];
    const float* w_off   = (const float*)d_in[3];
    const float* b_off   = (const float*)d_in[4];
    const float* w_mod   = (const float*)d_in[5];
    const float* b_mod   = (const float*)d_in[6];
    const float* w_reg   = (const float*)d_in[7];
    float* out = (float*)d_out;

    // workspace: Xt bf16 [NROW+1][192] | Wa2f | Wb2f | vt  (~19 MB)
    unsigned short* xt   = (unsigned short*)d_ws;
    unsigned short* wa2f = xt + (size_t)(NROW + 1) * C2B;
    unsigned short* wb2f = wa2f + NA;
    uint4* vt            = (uint4*)(wb2f + NW);   // 16B-aligned

    prep_kernel<<<PXB2 + PWBLK + 1, 256, 0, stream>>>(
        frame_i, frame_j, flow_ij, w_off, w_mod, w_reg, xt, wa2f, wb2f, vt);

    fused_kernel<<<GRID, 512, 0, stream>>>(
        xt, wa2f, wb2f, vt, b_off, b_mod, out);
}

// Round 10
// 112.101 us; speedup vs baseline: 1.8100x; 1.8100x over previous
//
#include <hip/hip_runtime.h>
#include <math.h>

#define BB   4
#define HH   96
#define WW   96
#define HW   (HH * WW)          // 9216
#define CIN  64
#define COUT 64
#define NPL  17                 // activation planes: fi 0-7, fj(phys) 8-15, flow 16
#define HWP  (HW + 1)           // uint4 per plane: HW positions + zero slot at HW
#define NROW (BB * HW)          // 36864
#define NSTRIP (NROW / 16)      // 2304 strips of 16 positions
#define BPX3 (NSTRIP / 8)       // 288 strips per XCD slice
#define NA   (9 * 5 * 2 * 512)  // wa2f elements (46080), fragment-dense
#define NW   (9 * 2 * 4 * 512)  // wb2f elements (36864), fragment-dense
#define PXB2 (NROW / 32)        // 1152 prep X-blocks (64 rows, half channels)
#define PWBLK 324               // weight blocks covering NA+NW elements
#define TSX  35                 // prep LDS tile stride (dwords), conflict-free
#define NIT  (NPL * 54)         // 918 staging items (17 planes x 54 positions)

typedef short v8s __attribute__((ext_vector_type(8)));   // 8 bf16 = 4 VGPRs
typedef float v4f __attribute__((ext_vector_type(4)));

__device__ __forceinline__ unsigned short f2bf(float f) {
    unsigned u = __float_as_uint(f);
    return (unsigned short)((u + 0x7FFFu + ((u >> 16) & 1u)) >> 16);  // RTN-even
}
__device__ __forceinline__ unsigned pack2(float a, float b) {
    return (unsigned)f2bf(a) | ((unsigned)f2bf(b) << 16);
}
__device__ __forceinline__ unsigned bil2(unsigned a, unsigned b, unsigned c,
                                         unsigned d, float w00, float w01,
                                         float w10, float w11) {
    float lo = w00 * __uint_as_float(a << 16) + w01 * __uint_as_float(b << 16)
             + w10 * __uint_as_float(c << 16) + w11 * __uint_as_float(d << 16);
    float hi = w00 * __uint_as_float(a & 0xffff0000u)
             + w01 * __uint_as_float(b & 0xffff0000u)
             + w10 * __uint_as_float(c & 0xffff0000u)
             + w11 * __uint_as_float(d & 0xffff0000u);
    return pack2(lo, hi);
}

// ---------------------------------------------------------------------------
// Prep R24: activations go to ONE plane-major store xp[b][pl][HWP] (16 B per
// position; consecutive positions 16 B apart). Planes: 0-7 fi chunks
// (natural: plane p = channels 8p..8p+7), 8-15 fj PHYS chunks (permuted pairs:
// phys pl holds orig chunk o=(pl>>1)+(pl&1)*4, so a deform lane's two K-chunks
// are adjacent planes), 16 flow {fl0,fl1,0..}. Index HW of each plane is a
// zero slot (OOB staging target). xt row layout is GONE.
// ---------------------------------------------------------------------------
__global__ __launch_bounds__(256) void prep_kernel(
    const float* __restrict__ fi, const float* __restrict__ fj,
    const float* __restrict__ fl, const float* __restrict__ w_off,
    const float* __restrict__ w_mod, const float* __restrict__ w_reg,
    uint4* __restrict__ xp, unsigned short* __restrict__ wa2f,
    unsigned short* __restrict__ wb2f)
{
    int blk = blockIdx.x;
    if (blk < PXB2) {
        __shared__ __align__(16) unsigned tile[64 * TSX];  // 9 KB
        int tid = threadIdx.x;
        int p = tid & 63, cg = tid >> 6;    // position, channel-group 0..3
        int u = blk >> 1, half = blk & 1;
        int r0 = u * 64;
        int b = r0 / HW;                    // 64-row strip never straddles b
        int hwb = r0 - b * HW;              // strip base within image
        int hw = hwb + p;
        uint4* xpb = xp + (size_t)b * NPL * HWP;
        if (half == 0) {                    // fi -> planes 0..7
            const float* pi = fi + (size_t)b * CIN * HW + hw;
#pragma unroll
            for (int d = 0; d < 8; ++d) {
                int c = cg * 16 + 2 * d;
                tile[p * TSX + cg * 8 + d] =
                    pack2(pi[(size_t)c * HW], pi[(size_t)(c + 1) * HW]);
            }
            __syncthreads();
#pragma unroll
            for (int i = 0; i < 2; ++i) {   // 512 plane-stores, coalesced
                int it = i * 256 + tid;
                int pl = it >> 6, rl = it & 63;
                const unsigned* s = &tile[rl * TSX + pl * 4];
                uint4 v = {s[0], s[1], s[2], s[3]};
                xpb[(size_t)pl * HWP + hwb + rl] = v;
            }
        } else {                            // fj(phys planes) + flow -> 8..16
            const float* pj = fj + (size_t)b * CIN * HW + hw;
#pragma unroll
            for (int d = 0; d < 8; ++d) {
                int c = cg * 16 + 2 * d;
                tile[p * TSX + cg * 8 + d] =
                    pack2(pj[(size_t)c * HW], pj[(size_t)(c + 1) * HW]);
            }
            if (cg == 0) {
                const float* pf = fl + (size_t)b * 2 * HW + hw;
                tile[p * TSX + 32] = pack2(pf[0], pf[HW]);
            }
            __syncthreads();
#pragma unroll
            for (int i = 0; i < 2; ++i) {   // 512 fj plane-stores (permuted)
                int it = i * 256 + tid;
                int pl = it >> 6, rl = it & 63;        // phys plane 0..7
                int o  = (pl >> 1) + (pl & 1) * 4;     // orig chunk
                const unsigned* s = &tile[rl * TSX + o * 4];
                uint4 v = {s[0], s[1], s[2], s[3]};
                xpb[(size_t)(8 + pl) * HWP + hwb + rl] = v;
            }
            if (tid < 64) {                 // flow plane 16
                uint4 v = {tile[tid * TSX + 32], 0u, 0u, 0u};
                xpb[(size_t)16 * HWP + hwb + tid] = v;
            }
        }
    } else if (blk < PXB2 + PWBLK) {
        int e = (blk - PXB2) * 256 + threadIdx.x;
        if (e < NA) {                       // wa2f, fragment-dense
            int t  = e / 5120;
            int r1 = e - t * 5120;
            int ks = r1 >> 10;
            int r2 = r1 & 1023;
            int nt = r2 >> 9;
            int l9 = r2 & 511;
            int l  = l9 >> 3, ee = l9 & 7;
            int m  = l & 15, g = l >> 4;
            int oc = nt * 16 + m;
            int ch = ks * 32 + g * 8 + ee;
            float v = 0.0f;
            if (oc < 27 && ch < 130) {
                if (oc < 18) v = w_off[((size_t)oc * 130 + ch) * 9 + t];
                else         v = w_mod[((size_t)(oc - 18) * 130 + ch) * 9 + t];
            }
            wa2f[e] = f2bf(v);
        } else {
            int e2 = e - NA;
            if (e2 < NW) {                  // wb2f, fragment-dense
                int k  = e2 >> 12;
                int r1 = e2 & 4095;
                int ks = r1 >> 11;
                int r2 = r1 & 2047;
                int nt = r2 >> 9;
                int l9 = r2 & 511;
                int l  = l9 >> 3, ee = l9 & 7;
                int m  = l & 15, g = l >> 4;
                int o  = nt * 16 + m;
                int c  = ks * 32 + g * 8 + ee;
                wb2f[e2] = f2bf(w_reg[((size_t)o * 64 + c) * 9 + k]);
            }
        }
    } else {
        if (threadIdx.x < BB * NPL) {       // 68 zero slots (index HW per plane)
            int bz = threadIdx.x / NPL, pl = threadIdx.x - bz * NPL;
            uint4 z = {0u, 0u, 0u, 0u};
            xp[((size_t)bz * NPL + pl) * HWP + HW] = z;
        }
    }
}

// ---------------------------------------------------------------------------
// Fused conv + deform. R24 = R21/R7 body (best verified) with plane-major
// staging: patchL[item], item = pl*54 + run*18 + r18 (linear, 14.7 KB).
// Staging reads xp plane runs (18 consecutive 16-B slots = 288 B contiguous);
// OOB positions read the plane's zero slot (index HW). ph1 ks=4 reads flow
// plane for g==0, zero-select for g>0 (replaces the old pad chunks 17-19).
// ph2 gathers identical to R7's vt path (planes 8+2g / 9+2g).
// NO extra live registers across phases (R5/R9 spill lesson).
// ---------------------------------------------------------------------------
__global__ __launch_bounds__(512, 8) void fused_kernel(
    const uint4* __restrict__ xp,
    const unsigned short* __restrict__ wa2f,
    const unsigned short* __restrict__ wb2f,
    const float* __restrict__ b_off, const float* __restrict__ b_mod,
    float* __restrict__ out)
{
    // pool: [0,14688) patchL (stage..barrier A) | [0,16384) red2 (after B)
    __shared__ __align__(16) unsigned char pool[16384];
    __shared__ __align__(16) float red1[8][8][64];    // 16 KB ph1 partials
    __shared__ float lraw[16 * 28];                   // 1.8 KB offsets/mods

    uint4* patchL = (uint4*)pool;
    float* red2   = (float*)pool;                     // [4][16][64]

    int tid = threadIdx.x;
    int l = tid & 63;
    int wid = __builtin_amdgcn_readfirstlane(tid >> 6);  // 0..7
    int m = l & 15, g = l >> 4;
    int strip = (blockIdx.x & 7) * BPX3 + (blockIdx.x >> 3);  // XCD-contiguous
    int b = strip / (HW / 16);              // wave-uniform
    int hw0 = (strip - b * (HW / 16)) * 16;
    int hw = hw0 + m;
    int x = hw % WW, y = hw / WW;
    int y0b = hw0 / WW, x0b = hw0 - y0b * WW;   // strip base (x0b mult of 16)

    const uint4* xpb = xp + (size_t)b * NPL * HWP;

    // ---- Stage 918 items: plane-major, contiguous 288-B runs ----
#pragma unroll
    for (int i = 0; i < 2; ++i) {
        int item = i * 512 + tid;
        if (item < NIT) {
            int pl  = item / 54;
            int rm  = item - pl * 54;
            int run = rm / 18;
            int r18 = rm - run * 18;
            int yy = y0b + run - 1;
            int xx = x0b - 1 + r18;
            bool ok = ((unsigned)yy < HH) && ((unsigned)xx < WW);
            int pos = ok ? (yy * WW + xx) : HW;     // HW = zero slot
            patchL[item] = xpb[(size_t)pl * HWP + pos];
        }
    }
    __syncthreads();                        // barrier S

    // ---- Phase 1: conv partials, 45 units over 8 waves (6/6/6/6/6/5/5/5) ----
    v4f acc0 = {0.f, 0.f, 0.f, 0.f};
    v4f acc1 = {0.f, 0.f, 0.f, 0.f};
    {
        int nu = (wid < 5) ? 6 : 5;         // wave-uniform unit count
#pragma unroll
        for (int i = 0; i < 6; ++i) {
            if (i < nu) {
                int u = wid + 8 * i;        // unit = t*5+ks, uniform
                int t = u / 5, ks = u - 5 * t;
                int r = (t / 3) * 18 + (t % 3) + m;
                v8s a;
                if (ks == 4) {              // flow plane; zero for g>0
                    uint4 t4 = patchL[16 * 54 + r];  // broadcast across g
                    if (g) t4 = (uint4){0u, 0u, 0u, 0u};
                    a = __builtin_bit_cast(v8s, t4);
                } else {
                    int pl = (ks == 0) ? g : (ks == 1) ? 4 + g
                           : (ks == 2) ? 8 + 2 * g : 9 + 2 * g;
                    a = *(const v8s*)&patchL[pl * 54 + r];
                }
                const unsigned short* wp =
                    wa2f + ((size_t)(u * 2)) * 512 + l * 8;
                v8s b0 = *(const v8s*)(wp);
                v8s b1 = *(const v8s*)(wp + 512);
                acc0 = __builtin_amdgcn_mfma_f32_16x16x32_bf16(a, b0, acc0, 0, 0, 0);
                acc1 = __builtin_amdgcn_mfma_f32_16x16x32_bf16(a, b1, acc1, 0, 0, 0);
            }
        }
    }

    {                                       // publish 8 dwords/lane (scalar)
#pragma unroll
        for (int j = 0; j < 4; ++j) red1[wid][j][l] = acc0[j];
#pragma unroll
        for (int j = 0; j < 4; ++j) red1[wid][4 + j][l] = acc1[j];
    }
    __syncthreads();                        // barrier A (patchL dead)

    {   // reduce + epilogue: wave w owns output-dword slot j = w
        int j = wid;
        float v = 0.f;
#pragma unroll
        for (int sw = 0; sw < 8; ++sw) v += red1[sw][j][l];
        int r = j & 3;
        int oc = (j < 4) ? m : 16 + m;
        int pos = g * 4 + r;
        if (oc < 18) {
            lraw[pos * 28 + oc] = v + b_off[oc];
        } else if (oc < 27) {
            lraw[pos * 28 + oc] =
                2.0f / (1.0f + __expf(-(v + b_mod[oc - 18])));
        }
    }
    __syncthreads();                        // barrier B (red1 dead, red2 born)

    // ---- Phase 2: wave w owns tap w; tap 8 split by ks to waves 6/7 ----
    v4f acc[4];
#pragma unroll
    for (int nt = 0; nt < 4; ++nt) acc[nt] = (v4f){0.f, 0.f, 0.f, 0.f};

    auto do_tap = [&](int k) {
        int ky = k / 3, kx = k - 3 * ky;
        float dy = lraw[m * 28 + 2 * k];
        float dx = lraw[m * 28 + 2 * k + 1];
        float mm = lraw[m * 28 + 18 + k];

        float py = (float)(y - 1 + ky) + dy;
        float px = (float)(x - 1 + kx) + dx;
        float fy = floorf(py), fx = floorf(px);
        int   y0 = (int)fy,    x0 = (int)fx;
        float wy = py - fy,    wx = px - fx;
        int   y1 = y0 + 1,     x1 = x0 + 1;

        bool y0v = (y0 >= 0) && (y0 < HH);
        bool y1v = (y1 >= 0) && (y1 < HH);
        bool x0v = (x0 >= 0) && (x0 < WW);
        bool x1v = (x1 >= 0) && (x1 < WW);

        float w00 = (1.f - wy) * (1.f - wx) * ((y0v && x0v) ? mm : 0.f);
        float w01 = (1.f - wy) * wx         * ((y0v && x1v) ? mm : 0.f);
        float w10 = wy * (1.f - wx)         * ((y1v && x0v) ? mm : 0.f);
        float w11 = wy * wx                 * ((y1v && x1v) ? mm : 0.f);

        int y0c = min(max(y0, 0), HH - 1), y1c = min(max(y1, 0), HH - 1);
        int x0c = min(max(x0, 0), WW - 1), x1c = min(max(x1, 0), WW - 1);
        int i00 = y0c * WW + x0c, i01 = y0c * WW + x1c;
        int i10 = y1c * WW + x0c, i11 = y1c * WW + x1c;

        const uint4* p0 = xpb + (size_t)(8 + 2 * g) * HWP;
        const uint4* p1 = p0 + HWP;

        uint4 a00 = p0[i00];
        uint4 a01 = p0[i01];
        uint4 a10 = p0[i10];
        uint4 a11 = p0[i11];
        uint4 c00 = p1[i00];
        uint4 c01 = p1[i01];
        uint4 c10 = p1[i10];
        uint4 c11 = p1[i11];

        uint4 ov0, ov1;
        ov0.x = bil2(a00.x, a01.x, a10.x, a11.x, w00, w01, w10, w11);
        ov0.y = bil2(a00.y, a01.y, a10.y, a11.y, w00, w01, w10, w11);
        ov0.z = bil2(a00.z, a01.z, a10.z, a11.z, w00, w01, w10, w11);
        ov0.w = bil2(a00.w, a01.w, a10.w, a11.w, w00, w01, w10, w11);
        ov1.x = bil2(c00.x, c01.x, c10.x, c11.x, w00, w01, w10, w11);
        ov1.y = bil2(c00.y, c01.y, c10.y, c11.y, w00, w01, w10, w11);
        ov1.z = bil2(c00.z, c01.z, c10.z, c11.z, w00, w01, w10, w11);
        ov1.w = bil2(c00.w, c01.w, c10.w, c11.w, w00, w01, w10, w11);
        v8s af0 = __builtin_bit_cast(v8s, ov0);
        v8s af1 = __builtin_bit_cast(v8s, ov1);

#pragma unroll
        for (int nt = 0; nt < 4; ++nt) {
            const unsigned short* wp0 =
                wb2f + ((size_t)((k * 2 + 0) * 4 + nt)) * 512 + l * 8;
            const unsigned short* wp1 =
                wb2f + ((size_t)((k * 2 + 1) * 4 + nt)) * 512 + l * 8;
            v8s bb0 = *(const v8s*)wp0;
            v8s bb1 = *(const v8s*)wp1;
            acc[nt] = __builtin_amdgcn_mfma_f32_16x16x32_bf16(af0, bb0, acc[nt], 0, 0, 0);
            acc[nt] = __builtin_amdgcn_mfma_f32_16x16x32_bf16(af1, bb1, acc[nt], 0, 0, 0);
        }
    };

    auto do_half = [&](int k, int ks) {
        int ky = k / 3, kx = k - 3 * ky;
        float dy = lraw[m * 28 + 2 * k];
        float dx = lraw[m * 28 + 2 * k + 1];
        float mm = lraw[m * 28 + 18 + k];

        float py = (float)(y - 1 + ky) + dy;
        float px = (float)(x - 1 + kx) + dx;
        float fy = floorf(py), fx = floorf(px);
        int   y0 = (int)fy,    x0 = (int)fx;
        float wy = py - fy,    wx = px - fx;
        int   y1 = y0 + 1,     x1 = x0 + 1;

        bool y0v = (y0 >= 0) && (y0 < HH);
        bool y1v = (y1 >= 0) && (y1 < HH);
        bool x0v = (x0 >= 0) && (x0 < WW);
        bool x1v = (x1 >= 0) && (x1 < WW);

        float w00 = (1.f - wy) * (1.f - wx) * ((y0v && x0v) ? mm : 0.f);
        float w01 = (1.f - wy) * wx         * ((y0v && x1v) ? mm : 0.f);
        float w10 = wy * (1.f - wx)         * ((y1v && x0v) ? mm : 0.f);
        float w11 = wy * wx                 * ((y1v && x1v) ? mm : 0.f);

        int y0c = min(max(y0, 0), HH - 1), y1c = min(max(y1, 0), HH - 1);
        int x0c = min(max(x0, 0), WW - 1), x1c = min(max(x1, 0), WW - 1);
        int i00 = y0c * WW + x0c, i01 = y0c * WW + x1c;
        int i10 = y1c * WW + x0c, i11 = y1c * WW + x1c;

        const uint4* pk = xpb + (size_t)(8 + 2 * g + ks) * HWP;
        uint4 a00 = pk[i00];
        uint4 a01 = pk[i01];
        uint4 a10 = pk[i10];
        uint4 a11 = pk[i11];

        uint4 ov;
        ov.x = bil2(a00.x, a01.x, a10.x, a11.x, w00, w01, w10, w11);
        ov.y = bil2(a00.y, a01.y, a10.y, a11.y, w00, w01, w10, w11);
        ov.z = bil2(a00.z, a01.z, a10.z, a11.z, w00, w01, w10, w11);
        ov.w = bil2(a00.w, a01.w, a10.w, a11.w, w00, w01, w10, w11);
        v8s af = __builtin_bit_cast(v8s, ov);

#pragma unroll
        for (int nt = 0; nt < 4; ++nt) {
            const unsigned short* wp =
                wb2f + ((size_t)((k * 2 + ks) * 4 + nt)) * 512 + l * 8;
            v8s bb = *(const v8s*)wp;
            acc[nt] = __builtin_amdgcn_mfma_f32_16x16x32_bf16(af, bb, acc[nt], 0, 0, 0);
        }
    };

    do_tap(wid);
    if (wid == 6) do_half(8, 0);
    if (wid == 7) do_half(8, 1);

    // ---- Two-stage cross-wave reduction (red2 = 4 buffers, 16 KB) ----
    if (wid >= 4) {                         // stage A: waves 4-7 publish
        float* rb = red2 + ((size_t)(wid - 4) * 16) * 64;
#pragma unroll
        for (int nt = 0; nt < 4; ++nt)
#pragma unroll
            for (int r = 0; r < 4; ++r)
                rb[(nt * 4 + r) * 64 + l] = acc[nt][r];
    }
    __syncthreads();                        // barrier C1
    if (wid < 4) {                          // stage B: waves 0-3 add in place
        float* rb = red2 + ((size_t)wid * 16) * 64;
#pragma unroll
        for (int nt = 0; nt < 4; ++nt)
#pragma unroll
            for (int r = 0; r < 4; ++r) {
                float t = rb[(nt * 4 + r) * 64 + l] + acc[nt][r];
                rb[(nt * 4 + r) * 64 + l] = t;
            }
    }
    __syncthreads();                        // barrier C2
    {   // stage C: wave w reduces slots {nt*4+r0, +1} over 4 buffers
        int nt = wid >> 1, r0 = (wid & 1) * 2;
        float v0 = 0.f, v1 = 0.f;
#pragma unroll
        for (int bu = 0; bu < 4; ++bu) {
            v0 += red2[((size_t)bu * 16 + nt * 4 + r0) * 64 + l];
            v1 += red2[((size_t)bu * 16 + nt * 4 + r0 + 1) * 64 + l];
        }
        float* op = out + ((size_t)(b * COUT + nt * 16 + m)) * HW
                  + hw0 + g * 4 + r0;
        float2 s2 = {v0, v1};
        *(float2*)op = s2;
    }
}

extern "C" void kernel_launch(void* const* d_in, const int* in_sizes, int n_in,
                              void* d_out, int out_size, void* d_ws, size_t ws_size,
                              hipStream_t stream)
{
    const float* frame_i = (const float*)d_in[0];
    const float* frame_j = (const float*)d_in[1];
    const float* flow_ij = (const float*)d_in[2];
    const float* w_off   = (const float*)d_in[3];
    const float* b_off   = (const float*)d_in[4];
    const float* w_mod   = (const float*)d_in[5];
    const float* b_mod   = (const float*)d_in[6];
    const float* w_reg   = (const float*)d_in[7];
    float* out = (float*)d_out;

    // workspace: xp uint4[BB*NPL*HWP] (~10 MB) | Wa2f | Wb2f
    uint4* xp = (uint4*)d_ws;
    unsigned short* wa2f = (unsigned short*)(xp + (size_t)BB * NPL * HWP);
    unsigned short* wb2f = wa2f + NA;

    prep_kernel<<<PXB2 + PWBLK + 1, 256, 0, stream>>>(
        frame_i, frame_j, flow_ij, w_off, w_mod, w_reg, xp, wa2f, wb2f);

    fused_kernel<<<NSTRIP, 512, 0, stream>>>(
        xp, wa2f, wb2f, b_off, b_mod, out);
}